// Round 2
// baseline (194.045 us; speedup 1.0000x reference)
//
#include <hip/hip_runtime.h>

// SheafConnectionLayer: out = x; for each edge-dir i in [0,2E):
//   i<E  : g=src[e], s=dst[e]  (e=i)
//   i>=E : g=dst[e], s=src[e]  (e=i-E)
//   m = T[i] @ x[g] - x[s]
//   out[s] += (alpha * softplus(raw_w[i]) / max(deg[s],1)) * m
//
// Memory-bound on the single streaming read of T (819 MB). 16 lanes per
// edge-dir: lane d computes output dim d, reading T row d as 4x float4.

static constexpr int DD = 16;

__global__ __launch_bounds__(256) void sheaf_edges(
    const float* __restrict__ x,
    const int*   __restrict__ ei,     // [2*E] : src rows then dst rows
    const float* __restrict__ deg,    // [N]
    const float* __restrict__ T,      // [2E][16][16]
    const float* __restrict__ raw_w,  // [2E]
    const float* __restrict__ alpha_p,// [1]
    float*       __restrict__ out,    // [N][16], pre-initialized to x
    int E, int E2)
{
    const float alpha = alpha_p[0];
    const int d = threadIdx.x & 15;                           // output dim
    const int group0  = (blockIdx.x * blockDim.x + threadIdx.x) >> 4;
    const int gstride = (gridDim.x * blockDim.x) >> 4;

    for (int i = group0; i < E2; i += gstride) {
        const int e = (i < E) ? i : (i - E);
        const int a = ei[e];          // src[e]
        const int b = ei[E + e];      // dst[e]
        const int g = (i < E) ? a : b;    // gather node
        const int s = (i < E) ? b : a;    // scatter node

        // T row for output dim d: 16 contiguous floats = 4x float4 (64B aligned)
        const float4* Tq = reinterpret_cast<const float4*>(
            T + (size_t)i * (DD * DD) + (size_t)d * DD);
        const float4 t0 = Tq[0], t1 = Tq[1], t2 = Tq[2], t3 = Tq[3];

        const float xg = x[(size_t)g * DD + d];
        const float xs = x[(size_t)s * DD + d];

        // dot = sum_k T[i][d][k] * x[g][k] via 16-wide shuffle broadcast
        float dot;
        dot  = t0.x * __shfl(xg,  0, 16);
        dot += t0.y * __shfl(xg,  1, 16);
        dot += t0.z * __shfl(xg,  2, 16);
        dot += t0.w * __shfl(xg,  3, 16);
        dot += t1.x * __shfl(xg,  4, 16);
        dot += t1.y * __shfl(xg,  5, 16);
        dot += t1.z * __shfl(xg,  6, 16);
        dot += t1.w * __shfl(xg,  7, 16);
        dot += t2.x * __shfl(xg,  8, 16);
        dot += t2.y * __shfl(xg,  9, 16);
        dot += t2.z * __shfl(xg, 10, 16);
        dot += t2.w * __shfl(xg, 11, 16);
        dot += t3.x * __shfl(xg, 12, 16);
        dot += t3.y * __shfl(xg, 13, 16);
        dot += t3.z * __shfl(xg, 14, 16);
        dot += t3.w * __shfl(xg, 15, 16);

        // softplus (numerically stable): max(x,0) + log1p(exp(-|x|))
        const float rw = raw_w[i];
        const float w  = fmaxf(rw, 0.0f) + log1pf(__expf(-fabsf(rw)));
        const float c  = alpha * w / fmaxf(deg[s], 1.0f);

        atomicAdd(out + (size_t)s * DD + d, c * (dot - xs));
    }
}

extern "C" void kernel_launch(void* const* d_in, const int* in_sizes, int n_in,
                              void* d_out, int out_size, void* d_ws, size_t ws_size,
                              hipStream_t stream) {
    const float* x       = (const float*)d_in[0];
    const int*   ei      = (const int*)  d_in[1];
    const float* deg     = (const float*)d_in[2];
    const float* T       = (const float*)d_in[3];
    const float* raw_w   = (const float*)d_in[4];
    const float* alpha_p = (const float*)d_in[5];
    float* out = (float*)d_out;

    const int E  = in_sizes[1] / 2;   // edge_index is (2, E)
    const int E2 = 2 * E;             // total edge-directions

    // out = x  (deterministic re-init every call; graph-capture safe)
    hipMemcpyAsync(out, x, sizeof(float) * (size_t)out_size,
                   hipMemcpyDeviceToDevice, stream);

    const int threads = 256;
    const int blocks  = 2048;         // ~8 blocks/CU, grid-stride over 2E
    sheaf_edges<<<blocks, threads, 0, stream>>>(x, ei, deg, T, raw_w, alpha_p,
                                                out, E, E2);
}